// Round 7
// baseline (161.783 us; speedup 1.0000x reference)
//
#include <hip/hip_runtime.h>
#include <math.h>

// Problem constants (match reference)
#define N_ATOMS 256
#define N_FEAT  128
#define BATCH   8
#define BINS    300
#define INV_STEP 149.5f        // 1/STEP, STEP = 2/(BINS-1)
#define ONE_OVER_2PI 0.15915494309189535f
#define INV_112 0.8928571428571429f   // 1/1.12
#define WIN 6                  // RBF window radius: exp(-36) ~ 2e-16, below f32 noise
#define WINW 13                // 2*WIN+1
#define NCOPY 4                // privatized histogram copies per wave

struct V3 { float x, y, z; };
__device__ __forceinline__ V3 v3sub(V3 a, V3 b) { return {a.x-b.x, a.y-b.y, a.z-b.z}; }
__device__ __forceinline__ float v3dot(V3 a, V3 b) { return a.x*b.x + a.y*b.y + a.z*b.z; }
__device__ __forceinline__ V3 v3cross(V3 a, V3 b) {
    return {a.y*b.z - a.z*b.y, a.z*b.x - a.x*b.z, a.x*b.y - a.y*b.x};
}
__device__ __forceinline__ V3 v3nrm(V3 a) {
    float r = __builtin_amdgcn_rsqf(v3dot(a, a));   // v_rsq_f32
    return {a.x*r, a.y*r, a.z*r};
}
__device__ __forceinline__ float clamp1(float x) { return fminf(1.0f, fmaxf(-1.0f, x)); }

// Branchless Cephes asinf: |x|<=0.5 poly; else pi/2 - 2*asin(sqrt((1-|x|)/2)).
__device__ __forceinline__ float asin_fast(float x) {
    float u = fabsf(x);
    bool big = u > 0.5f;
    float z = big ? 0.5f * (1.0f - u) : u * u;
    float s = big ? __builtin_amdgcn_sqrtf(z) : u;  // v_sqrt_f32
    float p = fmaf(z, 4.2163199048e-2f, 2.4181311049e-2f);
    p = fmaf(z, p, 4.5470025998e-2f);
    p = fmaf(z, p, 7.4953002686e-2f);
    p = fmaf(z, p, 1.6666752422e-1f);
    float r = fmaf(s * z, p, s);
    r = big ? (1.5707963267948966f - 2.0f * r) : r;
    return copysignf(r, x);
}

// writhe of segment pair (i,i+1),(j,j+1) from LDS coords
__device__ __forceinline__ float writhe_ij(const float* cs, int i, int j) {
    V3 pi  = {cs[i*3+0],     cs[i*3+1],     cs[i*3+2]};
    V3 pi1 = {cs[(i+1)*3+0], cs[(i+1)*3+1], cs[(i+1)*3+2]};
    V3 pj  = {cs[j*3+0],     cs[j*3+1],     cs[j*3+2]};
    V3 pj1 = {cs[(j+1)*3+0], cs[(j+1)*3+1], cs[(j+1)*3+2]};

    V3 d0 = v3nrm(v3sub(pj,  pi));
    V3 d1 = v3nrm(v3sub(pj1, pi));
    V3 d2 = v3nrm(v3sub(pj,  pi1));
    V3 d3 = v3nrm(v3sub(pj1, pi1));

    V3 c0 = v3nrm(v3cross(d0, d1));
    V3 c1 = v3nrm(v3cross(d1, d3));
    V3 c2 = v3nrm(v3cross(d3, d2));
    V3 c3 = v3nrm(v3cross(d2, d0));

    float omega = asin_fast(clamp1(v3dot(c0, c1)))
                + asin_fast(clamp1(v3dot(c1, c2)))
                + asin_fast(clamp1(v3dot(c2, c3)))
                + asin_fast(clamp1(v3dot(c3, c0)));

    float sg = v3dot(v3cross(v3sub(pj1, pj), v3sub(pi1, pi)), d0);
    float sign = (sg > 0.0f) ? 1.0f : ((sg < 0.0f) ? -1.0f : 0.0f);
    return omega * sign * ONE_OVER_2PI;
}

// One 64-lane WAVE per node n = b*256 + t. Incoming edges of node t: a in
// [0, t-2]; type-1 (segment (a,t)) exists iff t<=254; type-2 (segment
// (a-1,t-1)) exists iff a>=1; both share g = exp(-||c_a - c_t||^2).
// Lane handles a = lane, lane+64, ... (<=4 edges, 8 independent writhes).
// No block-wide atomics: denominator + bin-range via __shfl_xor butterflies.
__global__ __launch_bounds__(64) void fused_kernel(const float* __restrict__ coords,
                                                   const float* __restrict__ nf,
                                                   const float* __restrict__ basis,
                                                   float* __restrict__ out) {
    const int n = blockIdx.x;
    const int b = n >> 8;
    const int t = n & 255;
    const int lane = threadIdx.x;

    const float2* nf2 = reinterpret_cast<const float2*>(nf);
    float2* out2 = reinterpret_cast<float2*>(out);
    float2 mynf = nf2[(size_t)n * 64 + lane];   // prefetch early, hide HBM latency

    if (t < 2) {  // no incoming edges (block-uniform, before any barrier)
        out2[(size_t)n * 64 + lane] = mynf;
        return;
    }

    __shared__ float cs[N_ATOMS * 3];      // 3 KB
    __shared__ float h4[NCOPY * BINS];     // 4.8 KB

    #pragma unroll
    for (int r = 0; r < 12; ++r)           // 768 floats / 64 lanes
        cs[lane + 64 * r] = coords[(b << 8) * 3 + lane + 64 * r];
    for (int k = lane; k < NCOPY * BINS; k += 64) h4[k] = 0.0f;
    __syncthreads();                       // single-wave: near-free

    const int copy = lane & (NCOPY - 1);
    const int rot = lane % WINW;           // (lane%4, lane%13) distinct mod 52 -> <=2-way collisions
    const bool e1 = (t <= N_ATOMS - 2);
    const float ctx = cs[t*3+0], cty = cs[t*3+1], ctz = cs[t*3+2];

    float dsum = 0.0f;
    int kminl = BINS - 1, kmaxl = 0;

    for (int a = lane; a <= t - 2; a += 64) {
        float dx = cs[a*3+0] - ctx;
        float dy = cs[a*3+1] - cty;
        float dz = cs[a*3+2] - ctz;
        float g = __expf(-(dx*dx + dy*dy + dz*dz));
        dsum += g * ((e1 ? 1.0f : 0.0f) + (a >= 1 ? 1.0f : 0.0f));

        #pragma unroll
        for (int typ = 0; typ < 2; ++typ) {
            bool doit = (typ == 0) ? e1 : (a >= 1);
            if (doit) {
                float w = (typ == 0) ? writhe_ij(cs, a, t)
                                     : writhe_ij(cs, a - 1, t - 1);
                float p = (w + 1.0f) * INV_STEP;   // p - k = (w - c_k)/STEP
                int k0 = __float2int_rn(p);
                kminl = min(kminl, max(0, k0 - WIN));
                kmaxl = max(kmaxl, min(BINS - 1, k0 + WIN));
                int klo = k0 - WIN;
                #pragma unroll
                for (int m = 0; m < WINW; ++m) {
                    int mm = m + rot; if (mm >= WINW) mm -= WINW;
                    int k = klo + mm;
                    if (k >= 0 && k < BINS) {
                        float d = p - (float)k;
                        atomicAdd(&h4[copy * BINS + k], g * __expf(-d * d));
                    }
                }
            }
        }
    }

    // wave-wide reductions: denominator sum, touched-bin range (no LDS atomics)
    #pragma unroll
    for (int off = 32; off > 0; off >>= 1) {
        dsum += __shfl_xor(dsum, off, 64);
        kminl = min(kminl, __shfl_xor(kminl, off, 64));
        kmaxl = max(kmaxl, __shfl_xor(kmaxl, off, 64));
    }
    __syncthreads();

    // combine the 4 privatized copies over the touched range only
    for (int k = kminl + lane; k <= kmaxl; k += 64)
        h4[k] = h4[k] + h4[BINS + k] + h4[2 * BINS + k] + h4[3 * BINS + k];
    __syncthreads();

    // projection: lane owns feature pair (2*lane, 2*lane+1); h4[k] broadcasts
    const float2* b2 = reinterpret_cast<const float2*>(basis);
    float ax = 0.0f, ay = 0.0f;
    for (int k = kminl; k <= kmaxl; ++k) {
        float hv = h4[k];
        float2 bv = b2[k * (N_FEAT / 2) + lane];   // coalesced 512B, L2-resident
        ax = fmaf(hv, bv.x, ax);
        ay = fmaf(hv, bv.y, ay);
    }
    const float scale = INV_112 / dsum;
    out2[(size_t)n * 64 + lane] = make_float2(mynf.x + ax * scale,
                                              mynf.y + ay * scale);
}

extern "C" void kernel_launch(void* const* d_in, const int* in_sizes, int n_in,
                              void* d_out, int out_size, void* d_ws, size_t ws_size,
                              hipStream_t stream) {
    const float* coords = (const float*)d_in[0];   // (B*N, 3) f32
    const float* nf     = (const float*)d_in[1];   // (B*N, 128) f32
    const float* basis  = (const float*)d_in[2];   // (300, 128) f32
    float* out = (float*)d_out;                    // (B*N, 128) f32

    fused_kernel<<<BATCH * N_ATOMS, 64, 0, stream>>>(coords, nf, basis, out);
}

// Round 9
// 122.692 us; speedup vs baseline: 1.3186x; 1.3186x over previous
//
#include <hip/hip_runtime.h>
#include <math.h>

// Problem constants (match reference)
#define N_ATOMS 256
#define N_FEAT  128
#define BATCH   8
#define BINS    300
#define INV_STEP 149.5f        // 1/STEP, STEP = 2/(BINS-1)
#define ONE_OVER_2PI 0.15915494309189535f
#define INV_112 0.8928571428571429f   // 1/1.12
#define WIN 6                  // RBF window radius: exp(-36) ~ 2e-16, below f32 noise
#define WINW 13                // 2*WIN+1
#define NHIST 8                // privatized histogram copies (one per wave)

struct V3 { float x, y, z; };
__device__ __forceinline__ V3 v3sub(V3 a, V3 b) { return {a.x-b.x, a.y-b.y, a.z-b.z}; }
__device__ __forceinline__ float v3dot(V3 a, V3 b) { return a.x*b.x + a.y*b.y + a.z*b.z; }
__device__ __forceinline__ V3 v3cross(V3 a, V3 b) {
    return {a.y*b.z - a.z*b.y, a.z*b.x - a.x*b.z, a.x*b.y - a.y*b.x};
}
__device__ __forceinline__ V3 v3nrm(V3 a) {
    float r = __builtin_amdgcn_rsqf(v3dot(a, a));   // v_rsq_f32
    return {a.x*r, a.y*r, a.z*r};
}
__device__ __forceinline__ float clamp1(float x) { return fminf(1.0f, fmaxf(-1.0f, x)); }

// Branchless Cephes asinf: |x|<=0.5 poly; else pi/2 - 2*asin(sqrt((1-|x|)/2)).
__device__ __forceinline__ float asin_fast(float x) {
    float u = fabsf(x);
    bool big = u > 0.5f;
    float z = big ? 0.5f * (1.0f - u) : u * u;
    float s = big ? __builtin_amdgcn_sqrtf(z) : u;  // v_sqrt_f32
    float p = fmaf(z, 4.2163199048e-2f, 2.4181311049e-2f);
    p = fmaf(z, p, 4.5470025998e-2f);
    p = fmaf(z, p, 7.4953002686e-2f);
    p = fmaf(z, p, 1.6666752422e-1f);
    float r = fmaf(s * z, p, s);
    r = big ? (1.5707963267948966f - 2.0f * r) : r;
    return copysignf(r, x);
}

// writhe of segment pair (i,i+1),(j,j+1) from LDS coords
__device__ __forceinline__ float writhe_ij(const float* cs, int i, int j) {
    V3 pi  = {cs[i*3+0],     cs[i*3+1],     cs[i*3+2]};
    V3 pi1 = {cs[(i+1)*3+0], cs[(i+1)*3+1], cs[(i+1)*3+2]};
    V3 pj  = {cs[j*3+0],     cs[j*3+1],     cs[j*3+2]};
    V3 pj1 = {cs[(j+1)*3+0], cs[(j+1)*3+1], cs[(j+1)*3+2]};

    V3 d0 = v3nrm(v3sub(pj,  pi));
    V3 d1 = v3nrm(v3sub(pj1, pi));
    V3 d2 = v3nrm(v3sub(pj,  pi1));
    V3 d3 = v3nrm(v3sub(pj1, pi1));

    V3 c0 = v3nrm(v3cross(d0, d1));
    V3 c1 = v3nrm(v3cross(d1, d3));
    V3 c2 = v3nrm(v3cross(d3, d2));
    V3 c3 = v3nrm(v3cross(d2, d0));

    float omega = asin_fast(clamp1(v3dot(c0, c1)))
                + asin_fast(clamp1(v3dot(c1, c2)))
                + asin_fast(clamp1(v3dot(c2, c3)))
                + asin_fast(clamp1(v3dot(c3, c0)));

    float sg = v3dot(v3cross(v3sub(pj1, pj), v3sub(pi1, pi)), d0);
    float sign = (sg > 0.0f) ? 1.0f : ((sg < 0.0f) ? -1.0f : 0.0f);
    return omega * sign * ONE_OVER_2PI;
}

// One 512-thread block per node. blockIdx decomposed as b = blk&7, t = blk>>3
// so each CU's resident blocks span the full range of t (load de-aliasing).
// Edges of node t: a in [0,t-2]; type-1 (segment (a,t)) iff t<=254; type-2
// (segment (a-1,t-1)) iff a>=1; shared weight g = exp(-||c_a - c_t||^2).
// One writhe per thread: tid<256 -> type-1 edge a=tid; tid>=256 -> type-2
// edge a=tid-256. Histogram: 8 copies (copy=tid&7) + 13-phase rotation.
__global__ __launch_bounds__(512) void fused_kernel(const float* __restrict__ coords,
                                                    const float* __restrict__ nf,
                                                    const float* __restrict__ basis,
                                                    float* __restrict__ out) {
    const int blk = blockIdx.x;
    const int b = blk & 7;
    const int t = blk >> 3;
    const int n = (b << 8) | t;
    const int tid = threadIdx.x;

    float mynf = 0.0f;
    if (tid < N_FEAT) mynf = nf[(size_t)n * N_FEAT + tid];  // prefetch early

    if (t < 2) {  // no incoming edges (block-uniform, before any barrier)
        if (tid < N_FEAT) out[(size_t)n * N_FEAT + tid] = mynf;
        return;
    }

    __shared__ float cs[N_ATOMS * 3];        // 3 KB
    __shared__ float h8[NHIST * BINS];       // 9.6 KB
    __shared__ float part4[4 * N_FEAT];      // 2 KB
    __shared__ float sden;
    __shared__ int skmin, skmax;

    for (int idx = tid; idx < N_ATOMS * 3; idx += 512)
        cs[idx] = coords[(b << 8) * 3 + idx];
    for (int k = tid; k < NHIST * BINS; k += 512) h8[k] = 0.0f;
    if (tid == 0) { sden = 0.0f; skmin = BINS - 1; skmax = 0; }
    __syncthreads();

    const bool e1 = (t <= N_ATOMS - 2);
    const int typ = tid >> 8;                // 0: start-pair edge, 1: end-pair edge
    const int a = tid & 255;
    const bool active = (a <= t - 2) && (typ == 0 ? e1 : (a >= 1));

    float dsum = 0.0f;
    int kminl = BINS - 1, kmaxl = 0;

    if (active) {
        float dx = cs[a*3+0] - cs[t*3+0];
        float dy = cs[a*3+1] - cs[t*3+1];
        float dz = cs[a*3+2] - cs[t*3+2];
        float g = __expf(-(dx*dx + dy*dy + dz*dz));
        dsum = g;

        float w = (typ == 0) ? writhe_ij(cs, a, t) : writhe_ij(cs, a - 1, t - 1);
        float p = (w + 1.0f) * INV_STEP;     // p - k = (w - c_k)/STEP
        int k0 = __float2int_rn(p);
        kminl = max(0, k0 - WIN);
        kmaxl = min(BINS - 1, k0 + WIN);

        const int copy = tid & (NHIST - 1);
        const int rot = tid % WINW;
        int klo = k0 - WIN;
        #pragma unroll
        for (int m = 0; m < WINW; ++m) {
            int mm = m + rot; if (mm >= WINW) mm -= WINW;
            int k = klo + mm;
            if (k >= 0 && k < BINS) {
                float d = p - (float)k;
                atomicAdd(&h8[copy * BINS + k], g * __expf(-d * d));
            }
        }
    }

    // per-wave butterflies, then one LDS atomic per wave (8 waves)
    #pragma unroll
    for (int off = 32; off > 0; off >>= 1) {
        dsum += __shfl_xor(dsum, off, 64);
        kminl = min(kminl, __shfl_xor(kminl, off, 64));
        kmaxl = max(kmaxl, __shfl_xor(kmaxl, off, 64));
    }
    if ((tid & 63) == 0) {
        atomicAdd(&sden, dsum);
        atomicMin(&skmin, kminl);
        atomicMax(&skmax, kmaxl);
    }
    __syncthreads();

    // combine the 8 privatized copies over the touched range only
    const int kmin = skmin;
    const int kmax = skmax;
    for (int k = kmin + tid; k <= kmax; k += 512) {
        float s = h8[k];
        #pragma unroll
        for (int c = 1; c < NHIST; ++c) s += h8[c * BINS + k];
        h8[k] = s;
    }
    __syncthreads();

    // projection: 4 bin-quarters (q) x 128 features (f)
    const int len = kmax - kmin + 1;
    const int chunk = (len + 3) >> 2;
    const int q = tid >> 7;
    const int f = tid & (N_FEAT - 1);
    int ks = kmin + q * chunk;
    int ke = min(ks + chunk, kmin + len);
    float acc = 0.0f;
    for (int k = ks; k < ke; ++k)
        acc = fmaf(h8[k], basis[k * N_FEAT + f], acc);
    part4[q * N_FEAT + f] = acc;
    __syncthreads();

    if (tid < N_FEAT) {
        float s = part4[tid] + part4[N_FEAT + tid]
                + part4[2 * N_FEAT + tid] + part4[3 * N_FEAT + tid];
        out[(size_t)n * N_FEAT + tid] = mynf + s * (INV_112 / sden);
    }
}

extern "C" void kernel_launch(void* const* d_in, const int* in_sizes, int n_in,
                              void* d_out, int out_size, void* d_ws, size_t ws_size,
                              hipStream_t stream) {
    const float* coords = (const float*)d_in[0];   // (B*N, 3) f32
    const float* nf     = (const float*)d_in[1];   // (B*N, 128) f32
    const float* basis  = (const float*)d_in[2];   // (300, 128) f32
    float* out = (float*)d_out;                    // (B*N, 128) f32

    fused_kernel<<<BATCH * N_ATOMS, 512, 0, stream>>>(coords, nf, basis, out);
}

// Round 10
// 104.941 us; speedup vs baseline: 1.5417x; 1.1692x over previous
//
#include <hip/hip_runtime.h>
#include <math.h>

// Problem constants (match reference)
#define N_ATOMS 256
#define N_FEAT  128
#define BATCH   8
#define BINS    300
#define INV_STEP 149.5f        // 1/STEP, STEP = 2/(BINS-1)
#define ONE_OVER_2PI 0.15915494309189535f
#define INV_112 0.8928571428571429f   // 1/1.12
#define WIN 2                  // bins beyond |d|=2 contribute < exp(-9)*|basis| ~ 1e-5 << 0.0156 tol
#define WINW 5                 // 2*WIN+1
#define NHIST 8                // privatized histogram copies per node

struct V3 { float x, y, z; };
__device__ __forceinline__ V3 v3sub(V3 a, V3 b) { return {a.x-b.x, a.y-b.y, a.z-b.z}; }
__device__ __forceinline__ float v3dot(V3 a, V3 b) { return a.x*b.x + a.y*b.y + a.z*b.z; }
__device__ __forceinline__ V3 v3cross(V3 a, V3 b) {
    return {a.y*b.z - a.z*b.y, a.z*b.x - a.x*b.z, a.x*b.y - a.y*b.x};
}
__device__ __forceinline__ V3 v3nrm(V3 a) {
    float r = __builtin_amdgcn_rsqf(v3dot(a, a));   // v_rsq_f32
    return {a.x*r, a.y*r, a.z*r};
}
__device__ __forceinline__ float clamp1(float x) { return fminf(1.0f, fmaxf(-1.0f, x)); }

// Branchless Cephes asinf: |x|<=0.5 poly; else pi/2 - 2*asin(sqrt((1-|x|)/2)).
__device__ __forceinline__ float asin_fast(float x) {
    float u = fabsf(x);
    bool big = u > 0.5f;
    float z = big ? 0.5f * (1.0f - u) : u * u;
    float s = big ? __builtin_amdgcn_sqrtf(z) : u;  // v_sqrt_f32
    float p = fmaf(z, 4.2163199048e-2f, 2.4181311049e-2f);
    p = fmaf(z, p, 4.5470025998e-2f);
    p = fmaf(z, p, 7.4953002686e-2f);
    p = fmaf(z, p, 1.6666752422e-1f);
    float r = fmaf(s * z, p, s);
    r = big ? (1.5707963267948966f - 2.0f * r) : r;
    return copysignf(r, x);
}

// writhe of segment pair (i,i+1),(j,j+1) from LDS coords
__device__ __forceinline__ float writhe_ij(const float* cs, int i, int j) {
    V3 pi  = {cs[i*3+0],     cs[i*3+1],     cs[i*3+2]};
    V3 pi1 = {cs[(i+1)*3+0], cs[(i+1)*3+1], cs[(i+1)*3+2]};
    V3 pj  = {cs[j*3+0],     cs[j*3+1],     cs[j*3+2]};
    V3 pj1 = {cs[(j+1)*3+0], cs[(j+1)*3+1], cs[(j+1)*3+2]};

    V3 d0 = v3nrm(v3sub(pj,  pi));
    V3 d1 = v3nrm(v3sub(pj1, pi));
    V3 d2 = v3nrm(v3sub(pj,  pi1));
    V3 d3 = v3nrm(v3sub(pj1, pi1));

    V3 c0 = v3nrm(v3cross(d0, d1));
    V3 c1 = v3nrm(v3cross(d1, d3));
    V3 c2 = v3nrm(v3cross(d3, d2));
    V3 c3 = v3nrm(v3cross(d2, d0));

    float omega = asin_fast(clamp1(v3dot(c0, c1)))
                + asin_fast(clamp1(v3dot(c1, c2)))
                + asin_fast(clamp1(v3dot(c2, c3)))
                + asin_fast(clamp1(v3dot(c3, c0)));

    float sg = v3dot(v3cross(v3sub(pj1, pj), v3sub(pi1, pi)), d0);
    float sign = (sg > 0.0f) ? 1.0f : ((sg < 0.0f) ? -1.0f : 0.0f);
    return omega * sign * ONE_OVER_2PI;
}

// One 512-thread block per NODE PAIR (t0, t1) = (p+2, 255-p), same batch.
// Edge counts 2*t0-3 and 2*t1-3 sum to 508 for p>=1 (254 for p=0) -> every
// thread owns exactly one edge; near-perfect lane utilization and identical
// per-block work. Node tau edges: type-1 (segment (a,tau)), a in [0,tau-2],
// exists iff tau<=254; type-2 (segment (a-1,tau-1)), a in [1,tau-2]; both
// weighted g = exp(-||c_a - c_tau||^2). Enumeration: ee < E1 -> type-1 a=ee,
// else type-2 a = ee-E1+1, where E1 = (tau<=254) ? tau-1 : 0.
__global__ __launch_bounds__(512) void fused_kernel(const float* __restrict__ coords,
                                                    const float* __restrict__ nf,
                                                    const float* __restrict__ basis,
                                                    float* __restrict__ out) {
    const int blk = blockIdx.x;
    const int b = blk & 7;
    const int p = blk >> 3;            // pair index 0..126
    const int t0 = p + 2;              // 2..128
    const int t1 = 255 - p;            // 255..129
    const int tid = threadIdx.x;

    const int E0  = 2 * t0 - 3;                         // edges of node t0 (>=1)
    const int E1n = (t1 == 255) ? 253 : 2 * t1 - 3;     // edges of node t1

    float mynf = 0.0f;
    if (tid < 256) {                   // prefetch nf rows t0 (tid<128) and t1
        const int row = (tid >> 7) ? t1 : t0;
        mynf = nf[((size_t)((b << 8) | row)) * N_FEAT + (tid & 127)];
    }

    __shared__ float cs[N_ATOMS * 3];        // 3 KB
    __shared__ float h2[2 * NHIST * BINS];   // 19.2 KB (two 8-copy histograms)
    __shared__ float part[4 * N_FEAT];       // 2 KB
    __shared__ float sden[2];
    __shared__ int skmin[2], skmax[2];

    for (int idx = tid; idx < N_ATOMS * 3; idx += 512)
        cs[idx] = coords[(b << 8) * 3 + idx];
    for (int k = tid; k < 2 * NHIST * BINS; k += 512) h2[k] = 0.0f;
    if (tid < 2) { sden[tid] = 0.0f; skmin[tid] = BINS - 1; skmax[tid] = 0; }
    __syncthreads();

    int node = -1;
    int tau = t0;
    if (tid < E0) { node = 0; tau = t0; }
    else if (tid < E0 + E1n) { node = 1; tau = t1; }
    const int ee = (node == 1) ? tid - E0 : tid;

    float d0 = 0.0f, d1 = 0.0f;
    int kn0 = BINS - 1, kx0 = 0, kn1 = BINS - 1, kx1 = 0;

    if (node >= 0) {
        const int eT1 = (tau <= N_ATOMS - 2) ? tau - 1 : 0;
        const int typ = (ee < eT1) ? 0 : 1;
        const int a = (typ == 0) ? ee : ee - eT1 + 1;

        float dx = cs[a*3+0] - cs[tau*3+0];
        float dy = cs[a*3+1] - cs[tau*3+1];
        float dz = cs[a*3+2] - cs[tau*3+2];
        float g = __expf(-(dx*dx + dy*dy + dz*dz));

        float w = (typ == 0) ? writhe_ij(cs, a, tau) : writhe_ij(cs, a - 1, tau - 1);
        float pp = (w + 1.0f) * INV_STEP;    // pp - k = (w - c_k)/STEP
        int k0 = __float2int_rn(pp);
        int kmn = max(0, k0 - WIN);
        int kmx = min(BINS - 1, k0 + WIN);
        if (node == 0) { d0 = g; kn0 = kmn; kx0 = kmx; }
        else           { d1 = g; kn1 = kmn; kx1 = kmx; }

        const int copy = tid & (NHIST - 1);
        const int rot = tid % WINW;          // (tid&7, tid%5): <=2-way alias in a wave (free)
        const int base = (node * NHIST + copy) * BINS;
        const int klo = k0 - WIN;
        #pragma unroll
        for (int m = 0; m < WINW; ++m) {
            int mm = m + rot; if (mm >= WINW) mm -= WINW;
            int k = klo + mm;
            if (k >= 0 && k < BINS) {
                float dd = pp - (float)k;
                atomicAdd(&h2[base + k], g * __expf(-dd * dd));
            }
        }
    }

    // per-wave masked butterflies for both nodes, one LDS atomic set per wave
    #pragma unroll
    for (int off = 32; off > 0; off >>= 1) {
        d0 += __shfl_xor(d0, off, 64);
        d1 += __shfl_xor(d1, off, 64);
        kn0 = min(kn0, __shfl_xor(kn0, off, 64));
        kx0 = max(kx0, __shfl_xor(kx0, off, 64));
        kn1 = min(kn1, __shfl_xor(kn1, off, 64));
        kx1 = max(kx1, __shfl_xor(kx1, off, 64));
    }
    if ((tid & 63) == 0) {
        atomicAdd(&sden[0], d0);
        atomicAdd(&sden[1], d1);
        atomicMin(&skmin[0], kn0);
        atomicMax(&skmax[0], kx0);
        atomicMin(&skmin[1], kn1);
        atomicMax(&skmax[1], kx1);
    }
    __syncthreads();

    // combine the 8 privatized copies per node, over touched range only
    {
        const int nu = tid >> 8;             // 256 threads per node
        const int kmin = skmin[nu], kmax = skmax[nu];
        const int base = nu * NHIST * BINS;
        for (int k = kmin + (tid & 255); k <= kmax; k += 256) {
            float s = h2[base + k];
            #pragma unroll
            for (int c = 1; c < NHIST; ++c) s += h2[base + c * BINS + k];
            h2[base + k] = s;
        }
    }
    __syncthreads();

    // projection: 2 nodes x 2 bin-halves x 128 features
    {
        const int nu = tid >> 8;
        const int h = (tid >> 7) & 1;
        const int f = tid & 127;
        const int kmin = skmin[nu], kmax = skmax[nu];
        const int len = kmax - kmin + 1;
        const int half = (len + 1) >> 1;
        const int ks = kmin + h * half;
        const int ke = min(kmax + 1, ks + half);
        const int base = nu * NHIST * BINS;
        float acc = 0.0f;
        for (int k = ks; k < ke; ++k)
            acc = fmaf(h2[base + k], basis[k * N_FEAT + f], acc);
        part[((nu << 1) | h) * N_FEAT + f] = acc;
    }
    __syncthreads();

    if (tid < 256) {
        const int nu = tid >> 7;
        const int f = tid & 127;
        const int row = nu ? t1 : t0;
        const float scale = INV_112 / sden[nu];
        const float s = part[(nu << 1) * N_FEAT + f] + part[((nu << 1) | 1) * N_FEAT + f];
        out[((size_t)((b << 8) | row)) * N_FEAT + f] = mynf + s * scale;
    } else if (p == 0) {
        // passthrough rows t = 0, 1 (no incoming edges), handled by the (2,255) block
        const int tid2 = tid - 256;
        const int r = tid2 >> 7;
        const int f = tid2 & 127;
        const size_t idx = ((size_t)((b << 8) | r)) * N_FEAT + f;
        out[idx] = nf[idx];
    }
}

extern "C" void kernel_launch(void* const* d_in, const int* in_sizes, int n_in,
                              void* d_out, int out_size, void* d_ws, size_t ws_size,
                              hipStream_t stream) {
    const float* coords = (const float*)d_in[0];   // (B*N, 3) f32
    const float* nf     = (const float*)d_in[1];   // (B*N, 128) f32
    const float* basis  = (const float*)d_in[2];   // (300, 128) f32
    float* out = (float*)d_out;                    // (B*N, 128) f32

    fused_kernel<<<BATCH * 127, 512, 0, stream>>>(coords, nf, basis, out);
}